// Round 1
// baseline (569.287 us; speedup 1.0000x reference)
//
#include <hip/hip_runtime.h>
#include <math.h>

#define PI_F 3.14159265358979323846f

// ---------------- workspace layout (floats) ----------------
// QK   [128][4]          at WS_QK
// Wa   [2][64][4]        at WS_WA     (W_rad_s @ W_alpha)
// ba   [2][4]            at WS_BA     (b_rad_s @ W_alpha)
// bm   [2][128]          at WS_BM     (b_rad_s @ W_msg)
// Wm   [2][64][128]      at WS_WM     (W_rad_s @ W_msg)
// counts  [8192] int     at WS_COUNTS
// offsets [8193] int     at WS_OFFS
// cursor  [8192] int     at WS_CURSOR
// bucket  [262144] int   at WS_BUCKET
// lk   [N][4]            at WS_LK
// V    [N][128]          at WS_V
// out_pre [NQ][128]      at WS_OUTPRE

static const size_t WS_QK     = 128;
static const size_t WS_WA     = 640;
static const size_t WS_BA     = 1152;
static const size_t WS_BM     = 1160;
static const size_t WS_WM     = 1536;
static const size_t WS_COUNTS = 17920;
static const size_t WS_OFFS   = 26112;
static const size_t WS_CURSOR = 34816;
static const size_t WS_BUCKET = 43008;
static const size_t WS_LK     = 305152;
static const size_t WS_V      = 468992;
static const size_t WS_OUTPRE = 5711872;

__global__ void k_zero(int* p, int n) {
    int i = blockIdx.x * 256 + threadIdx.x;
    if (i < n) p[i] = 0;
}

// q = b_dst@Wq ; QK[c][h] = sum_d Wk[c][h*32+d]*q[h*32+d] / sqrt(32)
// Wa, ba, bm folded radial matrices
__global__ void k_prep(const float* b_dst, const float* Wq, const float* Wk,
                       const float* W_rad0, const float* b_rad0,
                       const float* W_rad1, const float* b_rad1,
                       const float* W_msg, const float* W_alpha,
                       float* QK, float* Wa, float* ba, float* bm) {
    __shared__ float qs[128];
    int t = threadIdx.x;
    if (t < 128) {
        float acc = 0.f;
        for (int c = 0; c < 128; ++c) acc += b_dst[c] * Wq[c * 128 + t];
        qs[t] = acc;
    }
    __syncthreads();
    if (t < 128) {
        const float invs = 0.17677669529663687f; // 1/sqrt(32)
        for (int h = 0; h < 4; ++h) {
            float acc = 0.f;
            for (int d = 0; d < 32; ++d) acc += Wk[t * 128 + h * 32 + d] * qs[h * 32 + d];
            QK[t * 4 + h] = acc * invs;
        }
    }
    for (int idx = t; idx < 512; idx += 256) {
        int s = idx >> 8, i = (idx >> 2) & 63, h = idx & 3;
        const float* Wr = s ? W_rad1 : W_rad0;
        float acc = 0.f;
        for (int u = 0; u < 64; ++u) acc += Wr[i * 64 + u] * W_alpha[u * 4 + h];
        Wa[idx] = acc;
    }
    if (t < 8) {
        int s = t >> 2, h = t & 3;
        const float* br = s ? b_rad1 : b_rad0;
        float acc = 0.f;
        for (int u = 0; u < 64; ++u) acc += br[u] * W_alpha[u * 4 + h];
        ba[t] = acc;
    }
    {
        int s = t >> 7, c = t & 127;
        const float* br = s ? b_rad1 : b_rad0;
        float acc = 0.f;
        for (int u = 0; u < 64; ++u) acc += br[u] * W_msg[u * 128 + c];
        bm[t] = acc;
    }
}

// Wm[s][i][c] = sum_u W_rad_s[i][u] * W_msg[u][c]   (16384 outputs)
__global__ void k_wm(const float* W_rad0, const float* W_rad1, const float* W_msg, float* Wm) {
    int tid = blockIdx.x * 256 + threadIdx.x;
    int s = tid >> 13, i = (tid >> 7) & 63, c = tid & 127;
    const float* Wr = s ? W_rad1 : W_rad0;
    float acc = 0.f;
    for (int u = 0; u < 64; ++u) acc += Wr[i * 64 + u] * W_msg[u * 128 + c];
    Wm[tid] = acc;
}

// lk[n][h] = sum_c f[n][c] * QK[c][h]
__global__ void k_lk(const float* f, const float* QK, float* lk, int Nn) {
    int tid = blockIdx.x * 256 + threadIdx.x;
    if (tid >= Nn * 4) return;
    int n = tid >> 2, h = tid & 3;
    float acc = 0.f;
    for (int c = 0; c < 128; ++c) acc += f[n * 128 + c] * QK[c * 4 + h];
    lk[tid] = acc;
}

// generic  out[M][128] = A[M][128] @ W[128][128] (+ bias)
// XOR-swizzled W^T in LDS; 8 cols x 8 rows per thread.
__global__ __launch_bounds__(256) void k_gemm128(const float* A, const float* W,
                                                 const float* bias, float* out, int M) {
    __shared__ float WT[128 * 128];
    int t = threadIdx.x;
    for (int idx = t; idx < 16384; idx += 256) {
        int k = idx >> 7, c = idx & 127;
        WT[c * 128 + (k ^ ((c & 7) << 2))] = W[idx];
    }
    __syncthreads();
    int m = t & 15, ng = t >> 4;
    int base = blockIdx.x * 128;
    float acc[8][8];
#pragma unroll
    for (int i = 0; i < 8; ++i)
#pragma unroll
        for (int j = 0; j < 8; ++j) acc[i][j] = 0.f;

    for (int kk = 0; kk < 128; kk += 4) {
        float4 wv[8], fa[8];
#pragma unroll
        for (int j = 0; j < 8; ++j) {
            int c = m + 16 * j;
            wv[j] = *(const float4*)&WT[c * 128 + (kk ^ ((c & 7) << 2))];
        }
#pragma unroll
        for (int i = 0; i < 8; ++i) {
            int row = base + ng * 8 + i;
            if (row >= M) row = M - 1;
            fa[i] = *(const float4*)&A[(size_t)row * 128 + kk];
        }
#pragma unroll
        for (int i = 0; i < 8; ++i)
#pragma unroll
            for (int j = 0; j < 8; ++j)
                acc[i][j] += fa[i].x * wv[j].x + fa[i].y * wv[j].y +
                             fa[i].z * wv[j].z + fa[i].w * wv[j].w;
    }
#pragma unroll
    for (int i = 0; i < 8; ++i) {
        int row = base + ng * 8 + i;
        if (row < M) {
#pragma unroll
            for (int j = 0; j < 8; ++j) {
                int c = m + 16 * j;
                float b = bias ? bias[c] : 0.f;
                out[(size_t)row * 128 + c] = acc[i][j] + b;
            }
        }
    }
}

__global__ void k_hist(const int* edge_dst, const int* scale_id, int* counts, int E) {
    int e = blockIdx.x * 256 + threadIdx.x;
    if (e < E) atomicAdd(&counts[edge_dst[e] * 2 + scale_id[e]], 1);
}

// single-block exclusive scan over nkey counters; writes offsets[nkey+1] and cursor copy
__global__ void k_scan(const int* counts, int* offsets, int* cursor, int nkey) {
    __shared__ int sdata[256];
    int t = threadIdx.x;
    int chunk = (nkey + 255) / 256;
    int sum = 0;
    for (int i = 0; i < chunk; ++i) {
        int idx = t * chunk + i;
        sum += (idx < nkey) ? counts[idx] : 0;
    }
    sdata[t] = sum;
    __syncthreads();
    for (int off = 1; off < 256; off <<= 1) {
        int v = (t >= off) ? sdata[t - off] : 0;
        __syncthreads();
        sdata[t] += v;
        __syncthreads();
    }
    int run = sdata[t] - sum;
    for (int i = 0; i < chunk; ++i) {
        int idx = t * chunk + i;
        if (idx < nkey) {
            offsets[idx] = run;
            cursor[idx] = run;
            run += counts[idx];
        }
    }
    if (t == 255) offsets[nkey] = sdata[255];
}

__global__ void k_scatter(const int* edge_dst, const int* scale_id, int* cursor,
                          int* bucket, int E) {
    int e = blockIdx.x * 256 + threadIdx.x;
    if (e < E) {
        int key = edge_dst[e] * 2 + scale_id[e];
        int pos = atomicAdd(&cursor[key], 1);
        bucket[pos] = e;
    }
}

// One wave per dst. Per scale segment: Wm panel (cols lane, lane+64) in 128 VGPRs.
// Per edge: radial g (1 exp/lane), butterfly-reduced alpha logits, 128-FMA msg matvec
// with g broadcast via LDS, sph-harm term, register softmax accumulation (no max pass).
__global__ __launch_bounds__(256) void k_main(
    const float* query_coord, const float* node_coord, const int* edge_src,
    const int* offsets, const int* bucket, const float* lk, const float* V,
    const float* Wa, const float* ba, const float* bm, const float* Wm,
    const float* W_sh, float* out_pre, int NQr) {
    __shared__ __align__(16) float gbuf[4][64];
    int t = threadIdx.x;
    int wid = t >> 6, lane = t & 63;
    int dst = blockIdx.x * 4 + wid;
    if (dst >= NQr) return;

    float qx = query_coord[dst * 3 + 0];
    float qy = query_coord[dst * 3 + 1];
    float qz = query_coord[dst * 3 + 2];

    float Wshr0[9], Wshr1[9];
#pragma unroll
    for (int i = 0; i < 9; ++i) {
        Wshr0[i] = W_sh[i * 128 + lane];
        Wshr1[i] = W_sh[i * 128 + 64 + lane];
    }

    float acc0 = 0.f, acc1 = 0.f;
    float den0 = 0.f, den1 = 0.f, den2 = 0.f, den3 = 0.f;
    const float s3 = 1.7320508075688772f, s15 = 3.872983346207417f, s5 = 2.23606797749979f;

    for (int sid = 0; sid < 2; ++sid) {
        int key = dst * 2 + sid;
        int p0i = offsets[key], p1i = offsets[key + 1];
        if (p0i == p1i) continue;

        float War0 = Wa[(sid * 64 + lane) * 4 + 0];
        float War1 = Wa[(sid * 64 + lane) * 4 + 1];
        float War2 = Wa[(sid * 64 + lane) * 4 + 2];
        float War3 = Wa[(sid * 64 + lane) * 4 + 3];
        float bav0 = ba[sid * 4 + 0], bav1 = ba[sid * 4 + 1];
        float bav2 = ba[sid * 4 + 2], bav3 = ba[sid * 4 + 3];
        float bmr0 = bm[sid * 128 + lane], bmr1 = bm[sid * 128 + 64 + lane];

        float wmA[64], wmB[64];
#pragma unroll
        for (int i = 0; i < 64; ++i) {
            wmA[i] = Wm[sid * 8192 + i * 128 + lane];
            wmB[i] = Wm[sid * 8192 + i * 128 + 64 + lane];
        }
        float roff = sid ? 0.2f : 0.1f;
        float rinvd = sid ? (1.0f / 3.8f) : (1.0f / 1.9f);

        for (int p = p0i; p < p1i; ++p) {
            int e = bucket[p];
            int src = edge_src[e];
            // issue gathers early
            float v0 = V[(size_t)src * 128 + lane];
            float v1 = V[(size_t)src * 128 + 64 + lane];
            float4 lkv = *(const float4*)&lk[src * 4];
            float vx = node_coord[src * 3 + 0] - qx;
            float vy = node_coord[src * 3 + 1] - qy;
            float vz = node_coord[src * 3 + 2] - qz;

            float r2 = vx * vx + vy * vy + vz * vz + 1e-12f;
            float r = sqrtf(r2);
            float xn = (r - roff) * rinvd;
            float tt = (xn - (float)lane * (1.0f / 63.0f)) * 64.0f;
            float su = fminf(fmaxf((xn - 0.8f) * 5.0f, 0.0f), 1.0f);
            float soft = 0.5f * (1.0f + __cosf(PI_F * su));
            float g = __expf(-0.5f * tt * tt) * soft;
            gbuf[wid][lane] = g;

            // alpha logits: butterfly reduce g_i * Wa[i][h]
            float pa0 = g * War0, pa1 = g * War1, pa2 = g * War2, pa3 = g * War3;
#pragma unroll
            for (int off = 32; off > 0; off >>= 1) {
                pa0 += __shfl_xor(pa0, off);
                pa1 += __shfl_xor(pa1, off);
                pa2 += __shfl_xor(pa2, off);
                pa3 += __shfl_xor(pa3, off);
            }
            float e0 = __expf(lkv.x + pa0 + bav0);
            float e1 = __expf(lkv.y + pa1 + bav1);
            float e2 = __expf(lkv.z + pa2 + bav2);
            float e3 = __expf(lkv.w + pa3 + bav3);
            den0 += e0; den1 += e1; den2 += e2; den3 += e3;

            // msg matvec: ms[c] = bm[c] + sum_i g_i * Wm[i][c]
            float ms0 = bmr0, ms1 = bmr1;
#pragma unroll
            for (int ii = 0; ii < 16; ++ii) {
                float4 g4 = *(const float4*)&gbuf[wid][ii * 4];
                ms0 += g4.x * wmA[ii * 4 + 0] + g4.y * wmA[ii * 4 + 1] +
                       g4.z * wmA[ii * 4 + 2] + g4.w * wmA[ii * 4 + 3];
                ms1 += g4.x * wmB[ii * 4 + 0] + g4.y * wmB[ii * 4 + 1] +
                       g4.z * wmB[ii * 4 + 2] + g4.w * wmB[ii * 4 + 3];
            }

            float rinv = 1.0f / r;
            float ux = vx * rinv, uy = vy * rinv, uz = vz * rinv;
            float sh1 = s3 * ux, sh2 = s3 * uy, sh3 = s3 * uz;
            float sh4 = s15 * ux * uy, sh5 = s15 * uy * uz;
            float sh6 = 0.5f * s5 * (3.0f * uz * uz - 1.0f);
            float sh7 = s15 * ux * uz;
            float sh8 = 0.5f * s15 * (ux * ux - uy * uy);
            float vsh0 = Wshr0[0] + sh1 * Wshr0[1] + sh2 * Wshr0[2] + sh3 * Wshr0[3] +
                         sh4 * Wshr0[4] + sh5 * Wshr0[5] + sh6 * Wshr0[6] +
                         sh7 * Wshr0[7] + sh8 * Wshr0[8];
            float vsh1 = Wshr1[0] + sh1 * Wshr1[1] + sh2 * Wshr1[2] + sh3 * Wshr1[3] +
                         sh4 * Wshr1[4] + sh5 * Wshr1[5] + sh6 * Wshr1[6] +
                         sh7 * Wshr1[7] + sh8 * Wshr1[8];

            float ve0 = v0 * ms0 + vsh0;
            float ve1 = v1 * ms1 + vsh1;
            float ph0 = (lane & 32) ? e1 : e0;
            float ph1 = (lane & 32) ? e3 : e2;
            acc0 += ph0 * ve0;
            acc1 += ph1 * ve1;
        }
    }
    float d0 = (lane & 32) ? den1 : den0;
    float d1 = (lane & 32) ? den3 : den2;
    out_pre[(size_t)dst * 128 + lane] = acc0 / (d0 + 1e-9f);
    out_pre[(size_t)dst * 128 + 64 + lane] = acc1 / (d1 + 1e-9f);
}

extern "C" void kernel_launch(void* const* d_in, const int* in_sizes, int n_in,
                              void* d_out, int out_size, void* d_ws, size_t ws_size,
                              hipStream_t stream) {
    const float* query_coord = (const float*)d_in[0];
    const float* node_feature = (const float*)d_in[1];
    const float* node_coord = (const float*)d_in[2];
    const int* edge_src = (const int*)d_in[3];
    const int* edge_dst = (const int*)d_in[4];
    const int* scale_id = (const int*)d_in[5];
    const float* b_dst = (const float*)d_in[6];
    const float* Wq = (const float*)d_in[7];
    const float* Wk = (const float*)d_in[8];
    const float* Wv = (const float*)d_in[9];
    const float* Wo = (const float*)d_in[10];
    const float* bo = (const float*)d_in[11];
    const float* W_rad0 = (const float*)d_in[12];
    const float* b_rad0 = (const float*)d_in[13];
    const float* W_rad1 = (const float*)d_in[14];
    const float* b_rad1 = (const float*)d_in[15];
    const float* W_msg = (const float*)d_in[16];
    const float* W_sh = (const float*)d_in[17];
    const float* W_alpha = (const float*)d_in[18];
    (void)n_in; (void)ws_size; (void)out_size;

    int NQr = in_sizes[0] / 3;      // 4096
    int Nn = in_sizes[1] / 128;     // 40960
    int E = in_sizes[3];            // 262144
    int nkey = NQr * 2;

    float* ws = (float*)d_ws;
    float* QK = ws + WS_QK;
    float* Wa = ws + WS_WA;
    float* ba = ws + WS_BA;
    float* bm = ws + WS_BM;
    float* Wm = ws + WS_WM;
    int* counts = (int*)(ws + WS_COUNTS);
    int* offsets = (int*)(ws + WS_OFFS);
    int* cursor = (int*)(ws + WS_CURSOR);
    int* bucket = (int*)(ws + WS_BUCKET);
    float* lk = ws + WS_LK;
    float* V = ws + WS_V;
    float* out_pre = ws + WS_OUTPRE;
    float* out = (float*)d_out;

    hipLaunchKernelGGL(k_zero, dim3((nkey + 255) / 256), dim3(256), 0, stream, counts, nkey);
    hipLaunchKernelGGL(k_prep, dim3(1), dim3(256), 0, stream,
                       b_dst, Wq, Wk, W_rad0, b_rad0, W_rad1, b_rad1, W_msg, W_alpha,
                       QK, Wa, ba, bm);
    hipLaunchKernelGGL(k_wm, dim3(64), dim3(256), 0, stream, W_rad0, W_rad1, W_msg, Wm);
    hipLaunchKernelGGL(k_lk, dim3((Nn * 4 + 255) / 256), dim3(256), 0, stream,
                       node_feature, QK, lk, Nn);
    hipLaunchKernelGGL(k_gemm128, dim3((Nn + 127) / 128), dim3(256), 0, stream,
                       node_feature, Wv, (const float*)nullptr, V, Nn);
    hipLaunchKernelGGL(k_hist, dim3((E + 255) / 256), dim3(256), 0, stream,
                       edge_dst, scale_id, counts, E);
    hipLaunchKernelGGL(k_scan, dim3(1), dim3(256), 0, stream, counts, offsets, cursor, nkey);
    hipLaunchKernelGGL(k_scatter, dim3((E + 255) / 256), dim3(256), 0, stream,
                       edge_dst, scale_id, cursor, bucket, E);
    hipLaunchKernelGGL(k_main, dim3((NQr + 3) / 4), dim3(256), 0, stream,
                       query_coord, node_coord, edge_src, offsets, bucket, lk, V,
                       Wa, ba, bm, Wm, W_sh, out_pre, NQr);
    hipLaunchKernelGGL(k_gemm128, dim3((NQr + 127) / 128), dim3(256), 0, stream,
                       out_pre, Wo, bo, out, NQr);
}

// Round 2
// 321.356 us; speedup vs baseline: 1.7715x; 1.7715x over previous
//
#include <hip/hip_runtime.h>
#include <hip/hip_bf16.h>
#include <math.h>

#define PI_F 3.14159265358979323846f

// ---------------- workspace layout (float slots) ----------------
static const size_t WS_QK     = 128;      // [128][4]
static const size_t WS_WA     = 640;      // [2][64][4]
static const size_t WS_BA     = 1152;     // [2][4]
static const size_t WS_BM     = 1160;     // [2][128]
static const size_t WS_WM     = 1536;     // [2][64][128]
static const size_t WS_COUNTS = 17920;    // [8192] int
static const size_t WS_OFFS   = 26112;    // [8193] int
static const size_t WS_CURSOR = 34816;    // [8192] int
static const size_t WS_PACKED = 43008;    // [E] int  (src | dst<<16), sorted by key=sid*NQ+dst
static const size_t WS_LK     = 305152;   // [N][4]
static const size_t WS_EDP    = 468992;   // [E][4]  {p0,p1,p2,p3}
static const size_t WS_EDG    = 1517568;  // [E][4]  {ux,uy,uz,xn}
static const size_t WS_VB     = 2566144;  // [N][128] bf16  (2 per float slot)
static const size_t WS_OUTPRE = 5187584;  // [NQ][128]
// end: 5711872 + 524288 = 6236160 floats = 24.94 MB (same footprint as round 1)

__global__ void k_zero(int* p, int n) {
    int i = blockIdx.x * 256 + threadIdx.x;
    if (i < n) p[i] = 0;
}

__global__ void k_prep(const float* b_dst, const float* Wq, const float* Wk,
                       const float* W_rad0, const float* b_rad0,
                       const float* W_rad1, const float* b_rad1,
                       const float* W_msg, const float* W_alpha,
                       float* QK, float* Wa, float* ba, float* bm) {
    __shared__ float qs[128];
    int t = threadIdx.x;
    if (t < 128) {
        float acc = 0.f;
        for (int c = 0; c < 128; ++c) acc += b_dst[c] * Wq[c * 128 + t];
        qs[t] = acc;
    }
    __syncthreads();
    if (t < 128) {
        const float invs = 0.17677669529663687f; // 1/sqrt(32)
        for (int h = 0; h < 4; ++h) {
            float acc = 0.f;
            for (int d = 0; d < 32; ++d) acc += Wk[t * 128 + h * 32 + d] * qs[h * 32 + d];
            QK[t * 4 + h] = acc * invs;
        }
    }
    for (int idx = t; idx < 512; idx += 256) {
        int s = idx >> 8, i = (idx >> 2) & 63, h = idx & 3;
        const float* Wr = s ? W_rad1 : W_rad0;
        float acc = 0.f;
        for (int u = 0; u < 64; ++u) acc += Wr[i * 64 + u] * W_alpha[u * 4 + h];
        Wa[idx] = acc;
    }
    if (t < 8) {
        int s = t >> 2, h = t & 3;
        const float* br = s ? b_rad1 : b_rad0;
        float acc = 0.f;
        for (int u = 0; u < 64; ++u) acc += br[u] * W_alpha[u * 4 + h];
        ba[t] = acc;
    }
    {
        int s = t >> 7, c = t & 127;
        const float* br = s ? b_rad1 : b_rad0;
        float acc = 0.f;
        for (int u = 0; u < 64; ++u) acc += br[u] * W_msg[u * 128 + c];
        bm[t] = acc;
    }
}

__global__ void k_wm(const float* W_rad0, const float* W_rad1, const float* W_msg, float* Wm) {
    int tid = blockIdx.x * 256 + threadIdx.x;
    int s = tid >> 13, i = (tid >> 7) & 63, c = tid & 127;
    const float* Wr = s ? W_rad1 : W_rad0;
    float acc = 0.f;
    for (int u = 0; u < 64; ++u) acc += Wr[i * 64 + u] * W_msg[u * 128 + c];
    Wm[tid] = acc;
}

// lk[n][h] = sum_c f[n][c] * QK[c][h]   (node-per-thread, coalesced float4)
__global__ void k_lk2(const float* f, const float* QK, float* lk, int Nn) {
    __shared__ float qks[512];
    int t = threadIdx.x;
    for (int i = t; i < 512; i += 256) qks[i] = QK[i];
    __syncthreads();
    int n = blockIdx.x * 256 + t;
    if (n >= Nn) return;
    float a0 = 0.f, a1 = 0.f, a2 = 0.f, a3 = 0.f;
    for (int k = 0; k < 128; k += 4) {
        float4 fv = *(const float4*)&f[(size_t)n * 128 + k];
        float4 q0 = *(const float4*)&qks[k * 4];
        float4 q1 = *(const float4*)&qks[(k + 1) * 4];
        float4 q2 = *(const float4*)&qks[(k + 2) * 4];
        float4 q3 = *(const float4*)&qks[(k + 3) * 4];
        a0 += fv.x * q0.x + fv.y * q1.x + fv.z * q2.x + fv.w * q3.x;
        a1 += fv.x * q0.y + fv.y * q1.y + fv.z * q2.y + fv.w * q3.y;
        a2 += fv.x * q0.z + fv.y * q1.z + fv.z * q2.z + fv.w * q3.z;
        a3 += fv.x * q0.w + fv.y * q1.w + fv.z * q2.w + fv.w * q3.w;
    }
    *(float4*)&lk[(size_t)n * 4] = make_float4(a0, a1, a2, a3);
}

// out[M][128] = A[M][128] @ W[128][128] (+bias), templated output type (f32 / bf16)
template <typename OUT>
__global__ __launch_bounds__(256) void k_gemm128(const float* A, const float* W,
                                                 const float* bias, OUT* out, int M) {
    __shared__ float WT[128 * 128];
    int t = threadIdx.x;
    for (int idx = t; idx < 16384; idx += 256) {
        int k = idx >> 7, c = idx & 127;
        WT[c * 128 + (k ^ ((c & 7) << 2))] = W[idx];
    }
    __syncthreads();
    int m = t & 15, ng = t >> 4;
    int base = blockIdx.x * 128;
    float acc[8][8];
#pragma unroll
    for (int i = 0; i < 8; ++i)
#pragma unroll
        for (int j = 0; j < 8; ++j) acc[i][j] = 0.f;

    for (int kk = 0; kk < 128; kk += 4) {
        float4 wv[8], fa[8];
#pragma unroll
        for (int j = 0; j < 8; ++j) {
            int c = m + 16 * j;
            wv[j] = *(const float4*)&WT[c * 128 + (kk ^ ((c & 7) << 2))];
        }
#pragma unroll
        for (int i = 0; i < 8; ++i) {
            int row = base + ng * 8 + i;
            if (row >= M) row = M - 1;
            fa[i] = *(const float4*)&A[(size_t)row * 128 + kk];
        }
#pragma unroll
        for (int i = 0; i < 8; ++i)
#pragma unroll
            for (int j = 0; j < 8; ++j)
                acc[i][j] += fa[i].x * wv[j].x + fa[i].y * wv[j].y +
                             fa[i].z * wv[j].z + fa[i].w * wv[j].w;
    }
#pragma unroll
    for (int i = 0; i < 8; ++i) {
        int row = base + ng * 8 + i;
        if (row < M) {
#pragma unroll
            for (int j = 0; j < 8; ++j) {
                int c = m + 16 * j;
                float b = bias ? bias[c] : 0.f;
                float v = acc[i][j] + b;
                out[(size_t)row * 128 + c] = (OUT)v;
            }
        }
    }
}

__global__ void k_hist(const int* edge_dst, const int* scale_id, int* counts, int E, int NQr) {
    int e = blockIdx.x * 256 + threadIdx.x;
    if (e < E) atomicAdd(&counts[scale_id[e] * NQr + edge_dst[e]], 1);
}

__global__ void k_scan(const int* counts, int* offsets, int* cursor, int nkey) {
    __shared__ int sdata[256];
    int t = threadIdx.x;
    int chunk = (nkey + 255) / 256;
    int sum = 0;
    for (int i = 0; i < chunk; ++i) {
        int idx = t * chunk + i;
        sum += (idx < nkey) ? counts[idx] : 0;
    }
    sdata[t] = sum;
    __syncthreads();
    for (int off = 1; off < 256; off <<= 1) {
        int v = (t >= off) ? sdata[t - off] : 0;
        __syncthreads();
        sdata[t] += v;
        __syncthreads();
    }
    int run = sdata[t] - sum;
    for (int i = 0; i < chunk; ++i) {
        int idx = t * chunk + i;
        if (idx < nkey) {
            offsets[idx] = run;
            cursor[idx] = run;
            run += counts[idx];
        }
    }
    if (t == 255) offsets[nkey] = sdata[255];
}

__global__ void k_scatter(const int* edge_src, const int* edge_dst, const int* scale_id,
                          int* cursor, int* packed, int E, int NQr) {
    int e = blockIdx.x * 256 + threadIdx.x;
    if (e < E) {
        int dst = edge_dst[e];
        int key = scale_id[e] * NQr + dst;
        int pos = atomicAdd(&cursor[key], 1);
        packed[pos] = edge_src[e] | (dst << 16);
    }
}

// Pass A: lane-per-edge. Computes geometry + radial window + softmax numerators.
__global__ __launch_bounds__(256) void k_edge(
    const int* packed, const int* offsets, const float* qc, const float* nc,
    const float* lk, const float* WaB, const float* baB,
    float* edP, float* edG, int NQr, int E) {
    __shared__ float WaS[512];
    __shared__ float baS[8];
    int t = threadIdx.x;
    for (int i = t; i < 512; i += 256) WaS[i] = WaB[i];
    if (t < 8) baS[t] = baB[t];
    __syncthreads();
    int p = blockIdx.x * 256 + t;
    if (p >= E) return;
    int bound = offsets[NQr];           // first scale-1 position
    int sid = (p >= bound) ? 1 : 0;
    int w = packed[p];
    int src = w & 0xFFFF;
    int dst = w >> 16;

    float qx = qc[dst * 3 + 0], qy = qc[dst * 3 + 1], qz = qc[dst * 3 + 2];
    float vx = nc[src * 3 + 0] - qx;
    float vy = nc[src * 3 + 1] - qy;
    float vz = nc[src * 3 + 2] - qz;
    float r = sqrtf(vx * vx + vy * vy + vz * vz + 1e-12f);
    float rinv = 1.0f / r;
    float ux = vx * rinv, uy = vy * rinv, uz = vz * rinv;

    float roff = sid ? 0.2f : 0.1f;
    float rdiv = sid ? (1.0f / 3.8f) : (1.0f / 1.9f);
    float xn = (r - roff) * rdiv;
    float su = fminf(fmaxf((xn - 0.8f) * 5.0f, 0.0f), 1.0f);
    float soft = 0.5f * (1.0f + __cosf(PI_F * su));

    float4 lkv = *(const float4*)&lk[(size_t)src * 4];

    const float* Wrow = WaS + sid * 256;
    float a0 = 0.f, a1 = 0.f, a2 = 0.f, a3 = 0.f;
    float ci = xn * 64.0f;
    const float step = 64.0f / 63.0f;
#pragma unroll 8
    for (int i = 0; i < 64; ++i) {
        float tt = ci;
        ci -= step;
        float graw = __expf(-0.5f * tt * tt);
        float4 wa = *(const float4*)&Wrow[i * 4];
        a0 = fmaf(graw, wa.x, a0);
        a1 = fmaf(graw, wa.y, a1);
        a2 = fmaf(graw, wa.z, a2);
        a3 = fmaf(graw, wa.w, a3);
    }
    float p0 = __expf(lkv.x + soft * a0 + baS[sid * 4 + 0]);
    float p1 = __expf(lkv.y + soft * a1 + baS[sid * 4 + 1]);
    float p2 = __expf(lkv.z + soft * a2 + baS[sid * 4 + 2]);
    float p3 = __expf(lkv.w + soft * a3 + baS[sid * 4 + 3]);
    *(float4*)&edP[(size_t)p * 4] = make_float4(p0, p1, p2, p3);
    *(float4*)&edG[(size_t)p * 4] = make_float4(ux, uy, uz, xn);
}

// Pass C: 2 waves per dst (64 columns each), deep software pipeline.
__global__ __launch_bounds__(256) void k_main2(
    const int* offsets, const int* packed, const float* edP, const float* edG,
    const __hip_bfloat16* Vb, const float* bm, const float* Wm, const float* W_sh,
    float* out_pre, int NQr) {
    __shared__ __align__(16) float gbuf[4][64];
    int t = threadIdx.x;
    int wid = t >> 6, lane = t & 63;
    int pair = wid >> 1, half = wid & 1;
    int dst = blockIdx.x * 2 + pair;
    if (dst >= NQr) return;
    int col = half * 64 + lane;

    float Wshr[9];
#pragma unroll
    for (int k = 0; k < 9; ++k) Wshr[k] = W_sh[k * 128 + col];

    const float s3 = 1.7320508075688772f, s15 = 3.872983346207417f, s5 = 2.23606797749979f;
    const float lane_c = (float)lane * (1.0f / 63.0f);

    float acc = 0.f, den = 0.f;

    for (int sid = 0; sid < 2; ++sid) {
        int key = sid * NQr + dst;
        int p0i = offsets[key];
        int n = offsets[key + 1] - p0i;
        if (n == 0) continue;

        float wm[64];
#pragma unroll
        for (int i = 0; i < 64; ++i) wm[i] = Wm[sid * 8192 + i * 128 + col];
        float bmr = bm[sid * 128 + col];

        // ---- pipeline prologue ----
        int q1 = p0i + (n > 1 ? 1 : 0);
        int q2 = p0i + (n > 2 ? 2 : (n - 1));
        int w0 = packed[p0i];
        int w1 = packed[q1];
        int wC = packed[q2];                         // pos idx+2 at loop top
        float4 Pa = *(const float4*)&edP[(size_t)p0i * 4];
        float4 Ga = *(const float4*)&edG[(size_t)p0i * 4];
        float4 Pb = *(const float4*)&edP[(size_t)q1 * 4];
        float4 Gb = *(const float4*)&edG[(size_t)q1 * 4];
        __hip_bfloat16 vA = Vb[(size_t)(w0 & 0xFFFF) * 128 + col];
        __hip_bfloat16 vB = Vb[(size_t)(w1 & 0xFFFF) * 128 + col];

#pragma unroll 3
        for (int idx = 0; idx < n; ++idx) {
            // --- issue stage ---
            int i3 = idx + 3; i3 = p0i + (i3 < n ? i3 : n - 1);
            int i2 = idx + 2; i2 = p0i + (i2 < n ? i2 : n - 1);
            int wD = packed[i3];                                    // W 3-ahead
            float4 Pc = *(const float4*)&edP[(size_t)i2 * 4];       // ED 2-ahead
            float4 Gc = *(const float4*)&edG[(size_t)i2 * 4];
            __hip_bfloat16 vC = Vb[(size_t)(wC & 0xFFFF) * 128 + col]; // V 2-ahead

            // --- compute with stage-a (loaded 2 iters ago) ---
            float xn = Ga.w;
            float tt = (xn - lane_c) * 64.0f;
            float graw = __expf(-0.5f * tt * tt);
            gbuf[wid][lane] = graw;
            float su = fminf(fmaxf((xn - 0.8f) * 5.0f, 0.0f), 1.0f);
            float soft = 0.5f * (1.0f + __cosf(PI_F * su));

            float ms = 0.f;
#pragma unroll
            for (int ii = 0; ii < 16; ++ii) {
                float4 g4 = *(const float4*)&gbuf[wid][ii * 4];
                ms = fmaf(g4.x, wm[ii * 4 + 0], ms);
                ms = fmaf(g4.y, wm[ii * 4 + 1], ms);
                ms = fmaf(g4.z, wm[ii * 4 + 2], ms);
                ms = fmaf(g4.w, wm[ii * 4 + 3], ms);
            }
            ms = fmaf(soft, ms, bmr);

            float ux = Ga.x, uy = Ga.y, uz = Ga.z;
            float sh1 = s3 * ux, sh2 = s3 * uy, sh3 = s3 * uz;
            float sh4 = s15 * ux * uy, sh5 = s15 * uy * uz;
            float sh6 = 0.5f * s5 * (3.0f * uz * uz - 1.0f);
            float sh7 = s15 * ux * uz;
            float sh8 = 0.5f * s15 * (ux * ux - uy * uy);
            float vsh = Wshr[0];
            vsh = fmaf(sh1, Wshr[1], vsh); vsh = fmaf(sh2, Wshr[2], vsh);
            vsh = fmaf(sh3, Wshr[3], vsh); vsh = fmaf(sh4, Wshr[4], vsh);
            vsh = fmaf(sh5, Wshr[5], vsh); vsh = fmaf(sh6, Wshr[6], vsh);
            vsh = fmaf(sh7, Wshr[7], vsh); vsh = fmaf(sh8, Wshr[8], vsh);

            float v = __bfloat162float(vA);
            float ve = fmaf(v, ms, vsh);
            float pa = half ? Pa.z : Pa.x;
            float pb = half ? Pa.w : Pa.y;
            float ph = (lane & 32) ? pb : pa;
            acc = fmaf(ph, ve, acc);
            den += ph;

            // --- rotate ---
            Pa = Pb; Ga = Gb; Pb = Pc; Gb = Gc;
            vA = vB; vB = vC;
            wC = wD;
        }
    }
    out_pre[(size_t)dst * 128 + col] = acc / (den + 1e-9f);
}

extern "C" void kernel_launch(void* const* d_in, const int* in_sizes, int n_in,
                              void* d_out, int out_size, void* d_ws, size_t ws_size,
                              hipStream_t stream) {
    const float* query_coord = (const float*)d_in[0];
    const float* node_feature = (const float*)d_in[1];
    const float* node_coord = (const float*)d_in[2];
    const int* edge_src = (const int*)d_in[3];
    const int* edge_dst = (const int*)d_in[4];
    const int* scale_id = (const int*)d_in[5];
    const float* b_dst = (const float*)d_in[6];
    const float* Wq = (const float*)d_in[7];
    const float* Wk = (const float*)d_in[8];
    const float* Wv = (const float*)d_in[9];
    const float* Wo = (const float*)d_in[10];
    const float* bo = (const float*)d_in[11];
    const float* W_rad0 = (const float*)d_in[12];
    const float* b_rad0 = (const float*)d_in[13];
    const float* W_rad1 = (const float*)d_in[14];
    const float* b_rad1 = (const float*)d_in[15];
    const float* W_msg = (const float*)d_in[16];
    const float* W_sh = (const float*)d_in[17];
    const float* W_alpha = (const float*)d_in[18];
    (void)n_in; (void)ws_size; (void)out_size;

    int NQr = in_sizes[0] / 3;      // 4096
    int Nn = in_sizes[1] / 128;     // 40960
    int E = in_sizes[3];            // 262144
    int nkey = NQr * 2;

    float* ws = (float*)d_ws;
    float* QK = ws + WS_QK;
    float* Wa = ws + WS_WA;
    float* ba = ws + WS_BA;
    float* bm = ws + WS_BM;
    float* Wm = ws + WS_WM;
    int* counts = (int*)(ws + WS_COUNTS);
    int* offsets = (int*)(ws + WS_OFFS);
    int* cursor = (int*)(ws + WS_CURSOR);
    int* packed = (int*)(ws + WS_PACKED);
    float* lk = ws + WS_LK;
    float* edP = ws + WS_EDP;
    float* edG = ws + WS_EDG;
    __hip_bfloat16* Vb = (__hip_bfloat16*)(ws + WS_VB);
    float* out_pre = ws + WS_OUTPRE;
    float* out = (float*)d_out;

    hipLaunchKernelGGL(k_zero, dim3((nkey + 255) / 256), dim3(256), 0, stream, counts, nkey);
    hipLaunchKernelGGL(k_prep, dim3(1), dim3(256), 0, stream,
                       b_dst, Wq, Wk, W_rad0, b_rad0, W_rad1, b_rad1, W_msg, W_alpha,
                       QK, Wa, ba, bm);
    hipLaunchKernelGGL(k_wm, dim3(64), dim3(256), 0, stream, W_rad0, W_rad1, W_msg, Wm);
    hipLaunchKernelGGL(k_lk2, dim3((Nn + 255) / 256), dim3(256), 0, stream,
                       node_feature, QK, lk, Nn);
    hipLaunchKernelGGL(k_gemm128<__hip_bfloat16>, dim3((Nn + 127) / 128), dim3(256), 0, stream,
                       node_feature, Wv, (const float*)nullptr, Vb, Nn);
    hipLaunchKernelGGL(k_hist, dim3((E + 255) / 256), dim3(256), 0, stream,
                       edge_dst, scale_id, counts, E, NQr);
    hipLaunchKernelGGL(k_scan, dim3(1), dim3(256), 0, stream, counts, offsets, cursor, nkey);
    hipLaunchKernelGGL(k_scatter, dim3((E + 255) / 256), dim3(256), 0, stream,
                       edge_src, edge_dst, scale_id, cursor, packed, E, NQr);
    hipLaunchKernelGGL(k_edge, dim3((E + 255) / 256), dim3(256), 0, stream,
                       packed, offsets, query_coord, node_coord, lk, Wa, ba,
                       edP, edG, NQr, E);
    hipLaunchKernelGGL(k_main2, dim3((NQr + 1) / 2), dim3(256), 0, stream,
                       offsets, packed, edP, edG, Vb, bm, Wm, W_sh, out_pre, NQr);
    hipLaunchKernelGGL(k_gemm128<float>, dim3((NQr + 127) / 128), dim3(256), 0, stream,
                       out_pre, Wo, bo, out, NQr);
}

// Round 3
// 233.709 us; speedup vs baseline: 2.4359x; 1.3750x over previous
//
#include <hip/hip_runtime.h>
#include <hip/hip_bf16.h>
#include <math.h>

#define PI_F 3.14159265358979323846f

typedef __attribute__((ext_vector_type(8))) short short8v;   // 8 bf16 (4 VGPR)
typedef __attribute__((ext_vector_type(4))) float f32x4;

__device__ __forceinline__ short f2bf(float x) {
    return __builtin_bit_cast(short, __float2bfloat16(x));
}
__device__ __forceinline__ float bf2f(unsigned short u) {
    return __uint_as_float(((unsigned)u) << 16);
}

// ---------------- workspace layout (float slots) ----------------
static const size_t WS_QK     = 128;      // [128][4]
static const size_t WS_WA     = 640;      // [2][64][4]
static const size_t WS_BA     = 1152;     // [2][4]
static const size_t WS_BM     = 1160;     // [2][128]
static const size_t WS_WMF    = 1536;     // [2][8][2][64][8] bf16 = 16384 bf16 = 8192 slots
static const size_t WS_WSHF   = 9728;     // [8][64][8] bf16 = 4096 bf16 = 2048 slots
static const size_t WS_DEN    = 11776;    // [NQ][4] f32 = 16384 slots
static const size_t WS_COUNTS = 28160;    // [8192] int
static const size_t WS_OFFS   = 36352;    // [8193] int
static const size_t WS_CURSOR = 44548;    // [8192] int
static const size_t WS_PACKED = 52744;    // [E] int  (src | dst<<16), sorted by key=sid*NQ+dst
static const size_t WS_LK     = 314888;   // [N][4]
static const size_t WS_EDP    = 478728;   // [E][4]  {p0,p1,p2,p3}
static const size_t WS_EDG    = 1527304;  // [E][4]  {ux,uy,uz,xn}
static const size_t WS_VB     = 2575880;  // [N][128] bf16
static const size_t WS_OUTPRE = 5197320;  // [NQ][128]
// end 5721608 slots = 22.9 MB (< 24.94 MB footprint proven in round 1)

// QK/Wa/ba/bm folds + zero the histogram counters (single block)
__global__ void k_prep(const float* b_dst, const float* Wq, const float* Wk,
                       const float* W_rad0, const float* b_rad0,
                       const float* W_rad1, const float* b_rad1,
                       const float* W_msg, const float* W_alpha,
                       float* QK, float* Wa, float* ba, float* bm,
                       int* counts, int nkey) {
    __shared__ float qs[128];
    int t = threadIdx.x;
    for (int i = t; i < nkey; i += 256) counts[i] = 0;
    if (t < 128) {
        float acc = 0.f;
        for (int c = 0; c < 128; ++c) acc += b_dst[c] * Wq[c * 128 + t];
        qs[t] = acc;
    }
    __syncthreads();
    if (t < 128) {
        const float invs = 0.17677669529663687f; // 1/sqrt(32)
        for (int h = 0; h < 4; ++h) {
            float acc = 0.f;
            for (int d = 0; d < 32; ++d) acc += Wk[t * 128 + h * 32 + d] * qs[h * 32 + d];
            QK[t * 4 + h] = acc * invs;
        }
    }
    for (int idx = t; idx < 512; idx += 256) {
        int s = idx >> 8, i = (idx >> 2) & 63, h = idx & 3;
        const float* Wr = s ? W_rad1 : W_rad0;
        float acc = 0.f;
        for (int u = 0; u < 64; ++u) acc += Wr[i * 64 + u] * W_alpha[u * 4 + h];
        Wa[idx] = acc;
    }
    if (t < 8) {
        int s = t >> 2, h = t & 3;
        const float* br = s ? b_rad1 : b_rad0;
        float acc = 0.f;
        for (int u = 0; u < 64; ++u) acc += br[u] * W_alpha[u * 4 + h];
        ba[t] = acc;
    }
    {
        int s = t >> 7, c = t & 127;
        const float* br = s ? b_rad1 : b_rad0;
        float acc = 0.f;
        for (int u = 0; u < 64; ++u) acc += br[u] * W_msg[u * 128 + c];
        bm[t] = acc;
    }
}

// Build MFMA B-fragments: WmF[sid][ct][kh][lane][j] = (W_rad_sid @ W_msg)[k][c] bf16
// with k = kh*32 + (lane>>4)*8 + j, c = ct*16 + (lane&15).
// WshF[ct][lane][j] = k<9 ? W_sh[k][c] : 0   (k = (lane>>4)*8 + j)
__global__ void k_fmt(const float* W_rad0, const float* W_rad1, const float* W_msg,
                      const float* W_sh, short* WmF, short* WshF) {
    int tid = blockIdx.x * 256 + threadIdx.x;
    if (tid < 16384) {
        int j = tid & 7, lane = (tid >> 3) & 63, kh = (tid >> 9) & 1;
        int ct = (tid >> 10) & 7, sid = tid >> 13;
        int k = kh * 32 + ((lane >> 4) << 3) + j;
        int c = ct * 16 + (lane & 15);
        const float* Wr = sid ? W_rad1 : W_rad0;
        float acc = 0.f;
        for (int u = 0; u < 64; ++u) acc += Wr[k * 64 + u] * W_msg[u * 128 + c];
        WmF[tid] = f2bf(acc);
    } else if (tid < 16384 + 4096) {
        int t2 = tid - 16384;
        int j = t2 & 7, lane = (t2 >> 3) & 63, ct = (t2 >> 9) & 7;
        int k = ((lane >> 4) << 3) + j;
        int c = ct * 16 + (lane & 15);
        WshF[t2] = f2bf(k < 9 ? W_sh[k * 128 + c] : 0.f);
    }
}

// lk[n][h] = sum_c f[n][c] * QK[c][h]
__global__ void k_lk2(const float* f, const float* QK, float* lk, int Nn) {
    __shared__ float qks[512];
    int t = threadIdx.x;
    for (int i = t; i < 512; i += 256) qks[i] = QK[i];
    __syncthreads();
    int n = blockIdx.x * 256 + t;
    if (n >= Nn) return;
    float a0 = 0.f, a1 = 0.f, a2 = 0.f, a3 = 0.f;
    for (int k = 0; k < 128; k += 4) {
        float4 fv = *(const float4*)&f[(size_t)n * 128 + k];
        float4 q0 = *(const float4*)&qks[k * 4];
        float4 q1 = *(const float4*)&qks[(k + 1) * 4];
        float4 q2 = *(const float4*)&qks[(k + 2) * 4];
        float4 q3 = *(const float4*)&qks[(k + 3) * 4];
        a0 += fv.x * q0.x + fv.y * q1.x + fv.z * q2.x + fv.w * q3.x;
        a1 += fv.x * q0.y + fv.y * q1.y + fv.z * q2.y + fv.w * q3.y;
        a2 += fv.x * q0.z + fv.y * q1.z + fv.z * q2.z + fv.w * q3.z;
        a3 += fv.x * q0.w + fv.y * q1.w + fv.z * q2.w + fv.w * q3.w;
    }
    *(float4*)&lk[(size_t)n * 4] = make_float4(a0, a1, a2, a3);
}

// out[M][128] = A[M][128] @ W[128][128] (+bias)
template <typename OUT>
__global__ __launch_bounds__(256) void k_gemm128(const float* A, const float* W,
                                                 const float* bias, OUT* out, int M) {
    __shared__ float WT[128 * 128];
    int t = threadIdx.x;
    for (int idx = t; idx < 16384; idx += 256) {
        int k = idx >> 7, c = idx & 127;
        WT[c * 128 + (k ^ ((c & 7) << 2))] = W[idx];
    }
    __syncthreads();
    int m = t & 15, ng = t >> 4;
    int base = blockIdx.x * 128;
    float acc[8][8];
#pragma unroll
    for (int i = 0; i < 8; ++i)
#pragma unroll
        for (int j = 0; j < 8; ++j) acc[i][j] = 0.f;

    for (int kk = 0; kk < 128; kk += 4) {
        float4 wv[8], fa[8];
#pragma unroll
        for (int j = 0; j < 8; ++j) {
            int c = m + 16 * j;
            wv[j] = *(const float4*)&WT[c * 128 + (kk ^ ((c & 7) << 2))];
        }
#pragma unroll
        for (int i = 0; i < 8; ++i) {
            int row = base + ng * 8 + i;
            if (row >= M) row = M - 1;
            fa[i] = *(const float4*)&A[(size_t)row * 128 + kk];
        }
#pragma unroll
        for (int i = 0; i < 8; ++i)
#pragma unroll
            for (int j = 0; j < 8; ++j)
                acc[i][j] += fa[i].x * wv[j].x + fa[i].y * wv[j].y +
                             fa[i].z * wv[j].z + fa[i].w * wv[j].w;
    }
#pragma unroll
    for (int i = 0; i < 8; ++i) {
        int row = base + ng * 8 + i;
        if (row < M) {
#pragma unroll
            for (int j = 0; j < 8; ++j) {
                int c = m + 16 * j;
                float b = bias ? bias[c] : 0.f;
                float v = acc[i][j] + b;
                out[(size_t)row * 128 + c] = (OUT)v;
            }
        }
    }
}

__global__ void k_hist(const int* edge_dst, const int* scale_id, int* counts, int E, int NQr) {
    int e = blockIdx.x * 256 + threadIdx.x;
    if (e < E) atomicAdd(&counts[scale_id[e] * NQr + edge_dst[e]], 1);
}

__global__ void k_scan(const int* counts, int* offsets, int* cursor, int nkey) {
    __shared__ int sdata[256];
    int t = threadIdx.x;
    int chunk = (nkey + 255) / 256;
    int sum = 0;
    for (int i = 0; i < chunk; ++i) {
        int idx = t * chunk + i;
        sum += (idx < nkey) ? counts[idx] : 0;
    }
    sdata[t] = sum;
    __syncthreads();
    for (int off = 1; off < 256; off <<= 1) {
        int v = (t >= off) ? sdata[t - off] : 0;
        __syncthreads();
        sdata[t] += v;
        __syncthreads();
    }
    int run = sdata[t] - sum;
    for (int i = 0; i < chunk; ++i) {
        int idx = t * chunk + i;
        if (idx < nkey) {
            offsets[idx] = run;
            cursor[idx] = run;
            run += counts[idx];
        }
    }
    if (t == 255) offsets[nkey] = sdata[255];
}

__global__ void k_scatter(const int* edge_src, const int* edge_dst, const int* scale_id,
                          int* cursor, int* packed, int E, int NQr) {
    int e = blockIdx.x * 256 + threadIdx.x;
    if (e < E) {
        int dst = edge_dst[e];
        int key = scale_id[e] * NQr + dst;
        int pos = atomicAdd(&cursor[key], 1);
        packed[pos] = edge_src[e] | (dst << 16);
    }
}

// lane-per-edge: geometry + softmax numerators (f32 alpha path)
__global__ __launch_bounds__(256) void k_edge(
    const int* packed, const int* offsets, const float* qc, const float* nc,
    const float* lk, const float* WaB, const float* baB,
    float* edP, float* edG, int NQr, int E) {
    __shared__ float WaS[512];
    __shared__ float baS[8];
    int t = threadIdx.x;
    for (int i = t; i < 512; i += 256) WaS[i] = WaB[i];
    if (t < 8) baS[t] = baB[t];
    __syncthreads();
    int p = blockIdx.x * 256 + t;
    if (p >= E) return;
    int bound = offsets[NQr];
    int sid = (p >= bound) ? 1 : 0;
    int w = packed[p];
    int src = w & 0xFFFF;
    int dst = w >> 16;

    float qx = qc[dst * 3 + 0], qy = qc[dst * 3 + 1], qz = qc[dst * 3 + 2];
    float vx = nc[src * 3 + 0] - qx;
    float vy = nc[src * 3 + 1] - qy;
    float vz = nc[src * 3 + 2] - qz;
    float r = sqrtf(vx * vx + vy * vy + vz * vz + 1e-12f);
    float rinv = 1.0f / r;
    float ux = vx * rinv, uy = vy * rinv, uz = vz * rinv;

    float roff = sid ? 0.2f : 0.1f;
    float rdiv = sid ? (1.0f / 3.8f) : (1.0f / 1.9f);
    float xn = (r - roff) * rdiv;
    float su = fminf(fmaxf((xn - 0.8f) * 5.0f, 0.0f), 1.0f);
    float soft = 0.5f * (1.0f + __cosf(PI_F * su));

    float4 lkv = *(const float4*)&lk[(size_t)src * 4];

    const float* Wrow = WaS + sid * 256;
    float a0 = 0.f, a1 = 0.f, a2 = 0.f, a3 = 0.f;
    float ci = xn * 64.0f;
    const float step = 64.0f / 63.0f;
#pragma unroll 8
    for (int i = 0; i < 64; ++i) {
        float tt = ci;
        ci -= step;
        float graw = __expf(-0.5f * tt * tt);
        float4 wa = *(const float4*)&Wrow[i * 4];
        a0 = fmaf(graw, wa.x, a0);
        a1 = fmaf(graw, wa.y, a1);
        a2 = fmaf(graw, wa.z, a2);
        a3 = fmaf(graw, wa.w, a3);
    }
    float p0 = __expf(lkv.x + soft * a0 + baS[sid * 4 + 0]);
    float p1 = __expf(lkv.y + soft * a1 + baS[sid * 4 + 1]);
    float p2 = __expf(lkv.z + soft * a2 + baS[sid * 4 + 2]);
    float p3 = __expf(lkv.w + soft * a3 + baS[sid * 4 + 3]);
    *(float4*)&edP[(size_t)p * 4] = make_float4(p0, p1, p2, p3);
    *(float4*)&edG[(size_t)p * 4] = make_float4(ux, uy, uz, xn);
}

// den[dst][h] = sum over both segments of edP[.][h]
__global__ void k_den(const int* offsets, const float* edP, float* den, int NQr) {
    int tid = blockIdx.x * 256 + threadIdx.x;
    if (tid >= NQr * 4) return;
    int dst = tid >> 2, h = tid & 3;
    float s = 0.f;
    for (int sid = 0; sid < 2; ++sid) {
        int key = sid * NQr + dst;
        int a = offsets[key], b = offsets[key + 1];
        for (int p = a; p < b; ++p) s += edP[(size_t)p * 4 + h];
    }
    den[tid] = s;
}

// MFMA edge aggregation: block = 1 dst, 4 waves = (sid, tile-parity).
// Per 16-edge tile: A = soft*G built in fragment layout (16 expf/lane),
// A2 = sph-harm channels; 24 mfma_f32_16x16x32_bf16; epilogue scales by V,p.
__global__ __launch_bounds__(256) void k_main3(
    const int* offsets, const int* packed, const float* edP, const float* edG,
    const __hip_bfloat16* Vb, const float* bm, const short* WmF, const short* WshF,
    const float* den, float* out_pre, int NQr) {
    __shared__ float part[4][128];
    int t = threadIdx.x;
    int w = t >> 6, lane = t & 63;
    int dst = blockIdx.x;
    int sid = w & 1, par = w >> 1;
    int m = lane & 15, grp = lane >> 4;
    const unsigned short* Vu = (const unsigned short*)Vb;

    float acc[8];
#pragma unroll
    for (int i = 0; i < 8; ++i) acc[i] = 0.f;

    int key = sid * NQr + dst;
    int s0 = offsets[key], s1 = offsets[key + 1];
    int n = s1 - s0;

    float bmv[8];
#pragma unroll
    for (int ct = 0; ct < 8; ++ct) bmv[ct] = bm[sid * 128 + ct * 16 + m];

    int ntiles = (n + 15) >> 4;
    for (int tl = par; tl < ntiles; tl += 2) {
        int q0 = s0 + tl * 16;
        // A-row load (row = m)
        int posA = q0 + m; if (posA >= s1) posA = s1 - 1;
        float4 G4 = *(const float4*)&edG[(size_t)posA * 4];
        // C-rows: grp*4+r
        int src_r[4]; float4 p4[4];
#pragma unroll
        for (int r = 0; r < 4; ++r) {
            int pos = q0 + grp * 4 + r;
            bool valid = pos < s1;
            if (!valid) pos = s1 - 1;
            int wv = packed[pos];
            src_r[r] = wv & 0xFFFF;
            float4 pv = *(const float4*)&edP[(size_t)pos * 4];
            if (!valid) pv = make_float4(0.f, 0.f, 0.f, 0.f);
            p4[r] = pv;
        }
        unsigned short vread[4][8];
#pragma unroll
        for (int r = 0; r < 4; ++r)
#pragma unroll
            for (int ct = 0; ct < 8; ++ct)
                vread[r][ct] = Vu[(size_t)src_r[r] * 128 + ct * 16 + m];

        // --- A fragment: soft * gaussian(xn), lane covers k = kh*32 + grp*8 + j ---
        float xn = G4.w;
        float su = fminf(fmaxf((xn - 0.8f) * 5.0f, 0.0f), 1.0f);
        float soft = 0.5f * (1.0f + __cosf(PI_F * su));
        short8v aG0, aG1;
#pragma unroll
        for (int j = 0; j < 8; ++j) {
            int k0 = grp * 8 + j;
            float d0 = (xn - (float)k0 * (1.0f / 63.0f)) * 64.0f;
            aG0[j] = f2bf(__expf(-0.5f * d0 * d0) * soft);
            int k1 = 32 + k0;
            float d1 = (xn - (float)k1 * (1.0f / 63.0f)) * 64.0f;
            aG1[j] = f2bf(__expf(-0.5f * d1 * d1) * soft);
        }
        // --- A2 fragment: sph-harm channels 0..8 ---
        float ux = G4.x, uy = G4.y, uz = G4.z;
        const float s3 = 1.7320508075688772f, s15 = 3.872983346207417f, s5 = 2.23606797749979f;
        float sh[9];
        sh[0] = 1.f; sh[1] = s3 * ux; sh[2] = s3 * uy; sh[3] = s3 * uz;
        sh[4] = s15 * ux * uy; sh[5] = s15 * uy * uz;
        sh[6] = 0.5f * s5 * (3.f * uz * uz - 1.f);
        sh[7] = s15 * ux * uz; sh[8] = 0.5f * s15 * (ux * ux - uy * uy);
        short8v aS;
#pragma unroll
        for (int j = 0; j < 8; ++j) {
            float v = (grp == 0) ? sh[j] : ((grp == 1 && j == 0) ? sh[8] : 0.f);
            aS[j] = f2bf(v);
        }

#pragma unroll
        for (int ct = 0; ct < 8; ++ct) {
            short8v b0 = *(const short8v*)&WmF[(((sid * 8 + ct) * 2 + 0) * 64 + lane) * 8];
            short8v b1 = *(const short8v*)&WmF[(((sid * 8 + ct) * 2 + 1) * 64 + lane) * 8];
            short8v bS = *(const short8v*)&WshF[(ct * 64 + lane) * 8];
            f32x4 cms = {0.f, 0.f, 0.f, 0.f};
            cms = __builtin_amdgcn_mfma_f32_16x16x32_bf16(aG0, b0, cms, 0, 0, 0);
            cms = __builtin_amdgcn_mfma_f32_16x16x32_bf16(aG1, b1, cms, 0, 0, 0);
            f32x4 csh = {0.f, 0.f, 0.f, 0.f};
            csh = __builtin_amdgcn_mfma_f32_16x16x32_bf16(aS, bS, csh, 0, 0, 0);
#pragma unroll
            for (int r = 0; r < 4; ++r) {
                float vf = bf2f(vread[r][ct]);
                float ms = cms[r] + bmv[ct];
                float ve = fmaf(vf, ms, csh[r]);
                float ph = (ct < 2) ? p4[r].x : (ct < 4) ? p4[r].y : (ct < 6) ? p4[r].z : p4[r].w;
                acc[ct] = fmaf(ph, ve, acc[ct]);
            }
        }
    }

#pragma unroll
    for (int i = 0; i < 8; ++i) {
        acc[i] += __shfl_xor(acc[i], 16);
        acc[i] += __shfl_xor(acc[i], 32);
    }
    if (lane < 16) {
#pragma unroll
        for (int ct = 0; ct < 8; ++ct) part[w][ct * 16 + lane] = acc[ct];
    }
    __syncthreads();
    if (t < 128) {
        float s = part[0][t] + part[1][t] + part[2][t] + part[3][t];
        float d = den[dst * 4 + (t >> 5)];
        out_pre[(size_t)dst * 128 + t] = s / (d + 1e-9f);
    }
}

extern "C" void kernel_launch(void* const* d_in, const int* in_sizes, int n_in,
                              void* d_out, int out_size, void* d_ws, size_t ws_size,
                              hipStream_t stream) {
    const float* query_coord = (const float*)d_in[0];
    const float* node_feature = (const float*)d_in[1];
    const float* node_coord = (const float*)d_in[2];
    const int* edge_src = (const int*)d_in[3];
    const int* edge_dst = (const int*)d_in[4];
    const int* scale_id = (const int*)d_in[5];
    const float* b_dst = (const float*)d_in[6];
    const float* Wq = (const float*)d_in[7];
    const float* Wk = (const float*)d_in[8];
    const float* Wv = (const float*)d_in[9];
    const float* Wo = (const float*)d_in[10];
    const float* bo = (const float*)d_in[11];
    const float* W_rad0 = (const float*)d_in[12];
    const float* b_rad0 = (const float*)d_in[13];
    const float* W_rad1 = (const float*)d_in[14];
    const float* b_rad1 = (const float*)d_in[15];
    const float* W_msg = (const float*)d_in[16];
    const float* W_sh = (const float*)d_in[17];
    const float* W_alpha = (const float*)d_in[18];
    (void)n_in; (void)ws_size; (void)out_size;

    int NQr = in_sizes[0] / 3;      // 4096
    int Nn = in_sizes[1] / 128;     // 40960
    int E = in_sizes[3];            // 262144
    int nkey = NQr * 2;

    float* ws = (float*)d_ws;
    float* QK = ws + WS_QK;
    float* Wa = ws + WS_WA;
    float* ba = ws + WS_BA;
    float* bm = ws + WS_BM;
    short* WmF = (short*)(ws + WS_WMF);
    short* WshF = (short*)(ws + WS_WSHF);
    float* den = ws + WS_DEN;
    int* counts = (int*)(ws + WS_COUNTS);
    int* offsets = (int*)(ws + WS_OFFS);
    int* cursor = (int*)(ws + WS_CURSOR);
    int* packed = (int*)(ws + WS_PACKED);
    float* lk = ws + WS_LK;
    float* edP = ws + WS_EDP;
    float* edG = ws + WS_EDG;
    __hip_bfloat16* Vb = (__hip_bfloat16*)(ws + WS_VB);
    float* out_pre = ws + WS_OUTPRE;
    float* out = (float*)d_out;

    hipLaunchKernelGGL(k_prep, dim3(1), dim3(256), 0, stream,
                       b_dst, Wq, Wk, W_rad0, b_rad0, W_rad1, b_rad1, W_msg, W_alpha,
                       QK, Wa, ba, bm, counts, nkey);
    hipLaunchKernelGGL(k_fmt, dim3(80), dim3(256), 0, stream,
                       W_rad0, W_rad1, W_msg, W_sh, WmF, WshF);
    hipLaunchKernelGGL(k_lk2, dim3((Nn + 255) / 256), dim3(256), 0, stream,
                       node_feature, QK, lk, Nn);
    hipLaunchKernelGGL(k_gemm128<__hip_bfloat16>, dim3((Nn + 127) / 128), dim3(256), 0, stream,
                       node_feature, Wv, (const float*)nullptr, Vb, Nn);
    hipLaunchKernelGGL(k_hist, dim3((E + 255) / 256), dim3(256), 0, stream,
                       edge_dst, scale_id, counts, E, NQr);
    hipLaunchKernelGGL(k_scan, dim3(1), dim3(256), 0, stream, counts, offsets, cursor, nkey);
    hipLaunchKernelGGL(k_scatter, dim3((E + 255) / 256), dim3(256), 0, stream,
                       edge_src, edge_dst, scale_id, cursor, packed, E, NQr);
    hipLaunchKernelGGL(k_edge, dim3((E + 255) / 256), dim3(256), 0, stream,
                       packed, offsets, query_coord, node_coord, lk, Wa, ba,
                       edP, edG, NQr, E);
    hipLaunchKernelGGL(k_den, dim3((NQr * 4 + 255) / 256), dim3(256), 0, stream,
                       offsets, edP, den, NQr);
    hipLaunchKernelGGL(k_main3, dim3(NQr), dim3(256), 0, stream,
                       offsets, packed, edP, edG, Vb, bm, WmF, WshF, den, out_pre, NQr);
    hipLaunchKernelGGL(k_gemm128<float>, dim3((NQr + 127) / 128), dim3(256), 0, stream,
                       out_pre, Wo, bo, out, NQr);
}

// Round 4
// 159.916 us; speedup vs baseline: 3.5599x; 1.4614x over previous
//
#include <hip/hip_runtime.h>
#include <hip/hip_bf16.h>
#include <math.h>

#define PI_F 3.14159265358979323846f

typedef __attribute__((ext_vector_type(8))) short short8v;   // 8 bf16 (4 VGPR)
typedef __attribute__((ext_vector_type(4))) float f32x4;

__device__ __forceinline__ short f2bf(float x) {
    return __builtin_bit_cast(short, __float2bfloat16(x));
}
__device__ __forceinline__ float bf2f(unsigned short u) {
    return __uint_as_float(((unsigned)u) << 16);
}
__device__ __forceinline__ void store_val(float* p, float v) { *p = v; }
__device__ __forceinline__ void store_val(unsigned short* p, float v) {
    *p = (unsigned short)f2bf(v);
}

// ---------------- workspace layout (float slots) ----------------
static const size_t WS_WA     = 0;        // [2][64][4] f32
static const size_t WS_BA     = 512;      // [2][4] f32
static const size_t WS_BM     = 520;      // [2][128] f32
static const size_t WS_WMF    = 776;      // [2][8][2][64][8] bf16 = 16384
static const size_t WS_WSHF   = 8968;     // [8][64][8] bf16 = 4096
static const size_t WS_QKF    = 11016;    // [4][64][8] bf16 = 2048
static const size_t WS_WVF    = 12040;    // [4][8][64][8] bf16 = 16384
static const size_t WS_WOF    = 20232;    // [4][8][64][8] bf16 = 16384
static const size_t WS_COUNTS = 28424;    // [8192] int
static const size_t WS_OFFS   = 36616;    // [8200] int
static const size_t WS_CURSOR = 44816;    // [8192] int
static const size_t WS_PACKED = 53008;    // [E] int (src | dst<<16)
static const size_t WS_LK     = 315152;   // [N][4] f32
static const size_t WS_EDP    = 478992;   // [E][4] f32 {p0..p3}
static const size_t WS_EDG    = 1527568;  // [E][4] f32 {ux,uy,uz,xn}
static const size_t WS_VB     = 2576144;  // [N][128] bf16
static const size_t WS_OUTPRE = 5197584;  // [NQ][128] f32
// end 5721872 slots = 22.89 MB (< 24.94 MB proven footprint)

// ---------------------------------------------------------------
// Block 0: fold QK/Wa/ba/bm, emit QKF frags, zero counts.
// Blocks 1..208: format WmF / WshF / WVF / WOF fragments.
__global__ __launch_bounds__(256) void k_prepfmt(
    const float* b_dst, const float* Wq, const float* Wk,
    const float* W_rad0, const float* b_rad0,
    const float* W_rad1, const float* b_rad1,
    const float* W_msg, const float* W_alpha, const float* Wv,
    const float* Wo, const float* W_sh,
    float* Wa, float* ba, float* bm,
    short* WmF, short* WshF, short* QKF, short* WVF, short* WOF,
    int* counts, int nkey) {
    __shared__ float qs_s[128];
    __shared__ float qk_s[512];
    int t = threadIdx.x;
    int b = blockIdx.x;
    if (b == 0) {
        for (int i = t; i < nkey; i += 256) counts[i] = 0;
        if (t < 128) {
            float acc = 0.f;
            for (int c = 0; c < 128; ++c) acc += b_dst[c] * Wq[c * 128 + t];
            qs_s[t] = acc;
        }
        __syncthreads();
        if (t < 128) {
            const float invs = 0.17677669529663687f; // 1/sqrt(32)
            for (int h = 0; h < 4; ++h) {
                float acc = 0.f;
                for (int d = 0; d < 32; ++d)
                    acc += Wk[t * 128 + h * 32 + d] * qs_s[h * 32 + d];
                qk_s[t * 4 + h] = acc * invs;
            }
        }
        for (int idx = t; idx < 512; idx += 256) {
            int s = idx >> 8, i = (idx >> 2) & 63, h = idx & 3;
            const float* Wr = s ? W_rad1 : W_rad0;
            float acc = 0.f;
            for (int u = 0; u < 64; ++u) acc += Wr[i * 64 + u] * W_alpha[u * 4 + h];
            Wa[idx] = acc;
        }
        if (t < 8) {
            int s = t >> 2, h = t & 3;
            const float* br = s ? b_rad1 : b_rad0;
            float acc = 0.f;
            for (int u = 0; u < 64; ++u) acc += br[u] * W_alpha[u * 4 + h];
            ba[t] = acc;
        }
        {
            int s = t >> 7, c = t & 127;
            const float* br = s ? b_rad1 : b_rad0;
            float acc = 0.f;
            for (int u = 0; u < 64; ++u) acc += br[u] * W_msg[u * 128 + c];
            bm[t] = acc;
        }
        __syncthreads();
        for (int idx = t; idx < 2048; idx += 256) {
            int j = idx & 7, lane = (idx >> 3) & 63, kh = idx >> 9;
            int k = kh * 32 + ((lane >> 4) << 3) + j;
            int col = lane & 15;
            QKF[idx] = f2bf(col < 4 ? qk_s[k * 4 + col] : 0.f);
        }
    } else {
        int item = (b - 1) * 256 + t;   // 0..53247
        if (item < 16384) {
            // WmF[sid][ct][kh][lane][j] = (W_rad_sid @ W_msg)[k][c]
            int j = item & 7, lane = (item >> 3) & 63, kh = (item >> 9) & 1;
            int ct = (item >> 10) & 7, sid = item >> 13;
            int k = kh * 32 + ((lane >> 4) << 3) + j;
            int c = ct * 16 + (lane & 15);
            const float* Wr = sid ? W_rad1 : W_rad0;
            float acc = 0.f;
            for (int u = 0; u < 64; ++u) acc += Wr[k * 64 + u] * W_msg[u * 128 + c];
            WmF[item] = f2bf(acc);
        } else if (item < 20480) {
            int i2 = item - 16384;
            int j = i2 & 7, lane = (i2 >> 3) & 63, ct = (i2 >> 9) & 7;
            int k = ((lane >> 4) << 3) + j;
            int c = ct * 16 + (lane & 15);
            WshF[i2] = f2bf(k < 9 ? W_sh[k * 128 + c] : 0.f);
        } else if (item < 36864) {
            int i2 = item - 20480;   // [kh][ct][lane][j]
            int j = i2 & 7, lane = (i2 >> 3) & 63, ct = (i2 >> 9) & 7, kh = (i2 >> 12) & 3;
            int k = kh * 32 + ((lane >> 4) << 3) + j;
            int c = ct * 16 + (lane & 15);
            WVF[i2] = f2bf(Wv[k * 128 + c]);
        } else {
            int i2 = item - 36864;
            int j = i2 & 7, lane = (i2 >> 3) & 63, ct = (i2 >> 9) & 7, kh = (i2 >> 12) & 3;
            int k = kh * 32 + ((lane >> 4) << 3) + j;
            int c = ct * 16 + (lane & 15);
            WOF[i2] = f2bf(Wo[k * 128 + c]);
        }
    }
}

// ---------------------------------------------------------------
// MFMA GEMM: out[M][128] = A[M][128] @ W (+bias); optional lk = A @ QK.
// One 16-row tile per wave. B fragments preformatted (WF/QKF).
template <typename OUT, bool LK>
__global__ __launch_bounds__(256) void k_mgemm(
    const float* A, const short* WF, const float* bias, OUT* out,
    float* lk, const short* QKF, int M) {
    int t = threadIdx.x;
    int w = t >> 6, lane = t & 63;
    int m = lane & 15, grp = lane >> 4;
    int row0 = (blockIdx.x * 4 + w) * 16;
    if (row0 >= M) return;

    short8v a[4];
#pragma unroll
    for (int kh = 0; kh < 4; ++kh) {
        const float* ap = &A[(size_t)(row0 + m) * 128 + kh * 32 + grp * 8];
        float4 f0 = *(const float4*)ap;
        float4 f1 = *(const float4*)(ap + 4);
        a[kh][0] = f2bf(f0.x); a[kh][1] = f2bf(f0.y);
        a[kh][2] = f2bf(f0.z); a[kh][3] = f2bf(f0.w);
        a[kh][4] = f2bf(f1.x); a[kh][5] = f2bf(f1.y);
        a[kh][6] = f2bf(f1.z); a[kh][7] = f2bf(f1.w);
    }
    if constexpr (LK) {
        f32x4 cl = {0.f, 0.f, 0.f, 0.f};
#pragma unroll
        for (int kh = 0; kh < 4; ++kh) {
            short8v qb = *(const short8v*)&QKF[(kh * 64 + lane) * 8];
            cl = __builtin_amdgcn_mfma_f32_16x16x32_bf16(a[kh], qb, cl, 0, 0, 0);
        }
        if (m < 4) {
#pragma unroll
            for (int r = 0; r < 4; ++r)
                lk[(size_t)(row0 + grp * 4 + r) * 4 + m] = cl[r];
        }
    }
#pragma unroll
    for (int ct = 0; ct < 8; ++ct) {
        f32x4 c = {0.f, 0.f, 0.f, 0.f};
#pragma unroll
        for (int kh = 0; kh < 4; ++kh) {
            short8v bf = *(const short8v*)&WF[((kh * 8 + ct) * 64 + lane) * 8];
            c = __builtin_amdgcn_mfma_f32_16x16x32_bf16(a[kh], bf, c, 0, 0, 0);
        }
        float bb = bias ? bias[ct * 16 + m] : 0.f;
#pragma unroll
        for (int r = 0; r < 4; ++r)
            store_val(&out[(size_t)(row0 + grp * 4 + r) * 128 + ct * 16 + m], c[r] + bb);
    }
}

// ---------------------------------------------------------------
__global__ void k_hist(const int* edge_dst, const int* scale_id, int* counts, int E, int NQr) {
    int e = blockIdx.x * 256 + threadIdx.x;
    if (e < E) atomicAdd(&counts[scale_id[e] * NQr + edge_dst[e]], 1);
}

__global__ void k_scan(const int* counts, int* offsets, int* cursor, int nkey) {
    __shared__ int sdata[256];
    int t = threadIdx.x;
    int chunk = (nkey + 255) / 256;
    int sum = 0;
    for (int i = 0; i < chunk; ++i) {
        int idx = t * chunk + i;
        sum += (idx < nkey) ? counts[idx] : 0;
    }
    sdata[t] = sum;
    __syncthreads();
    for (int off = 1; off < 256; off <<= 1) {
        int v = (t >= off) ? sdata[t - off] : 0;
        __syncthreads();
        sdata[t] += v;
        __syncthreads();
    }
    int run = sdata[t] - sum;
    for (int i = 0; i < chunk; ++i) {
        int idx = t * chunk + i;
        if (idx < nkey) {
            offsets[idx] = run;
            cursor[idx] = run;
            run += counts[idx];
        }
    }
    if (t == 255) offsets[nkey] = sdata[255];
}

__global__ void k_scatter(const int* edge_src, const int* edge_dst, const int* scale_id,
                          int* cursor, int* packed, int E, int NQr) {
    int e = blockIdx.x * 256 + threadIdx.x;
    if (e < E) {
        int dst = edge_dst[e];
        int key = scale_id[e] * NQr + dst;
        int pos = atomicAdd(&cursor[key], 1);
        packed[pos] = edge_src[e] | (dst << 16);
    }
}

// ---------------------------------------------------------------
// lane-per-edge: geometry + softmax numerators (chain-exp radial basis).
__global__ __launch_bounds__(256) void k_edge(
    const int* packed, const int* offsets, const float* qc, const float* nc,
    const float* lk, const float* WaB, const float* baB,
    float* edP, float* edG, int NQr, int E) {
    __shared__ float WaS[512];
    __shared__ float baS[8];
    int t = threadIdx.x;
    for (int i = t; i < 512; i += 256) WaS[i] = WaB[i];
    if (t < 8) baS[t] = baB[t];
    __syncthreads();
    int p = blockIdx.x * 256 + t;
    if (p >= E) return;
    int bound = offsets[NQr];
    int sid = (p >= bound) ? 1 : 0;
    int wv = packed[p];
    int src = wv & 0xFFFF;
    int dst = wv >> 16;

    float qx = qc[dst * 3 + 0], qy = qc[dst * 3 + 1], qz = qc[dst * 3 + 2];
    float vx = nc[src * 3 + 0] - qx;
    float vy = nc[src * 3 + 1] - qy;
    float vz = nc[src * 3 + 2] - qz;
    float r = sqrtf(vx * vx + vy * vy + vz * vz + 1e-12f);
    float rinv = 1.0f / r;
    float ux = vx * rinv, uy = vy * rinv, uz = vz * rinv;

    float roff = sid ? 0.2f : 0.1f;
    float rdiv = sid ? (1.0f / 3.8f) : (1.0f / 1.9f);
    float xn = (r - roff) * rdiv;
    float su = fminf(fmaxf((xn - 0.8f) * 5.0f, 0.0f), 1.0f);
    float soft = 0.5f * (1.0f + __cosf(PI_F * su));

    float4 lkv = *(const float4*)&lk[(size_t)src * 4];

    const float qs = 64.f / 63.f;
    const float Qc = __expf(-qs * qs);
    const float* Wrow = WaS + sid * 256;
    float a0 = 0.f, a1 = 0.f, a2 = 0.f, a3 = 0.f;
#pragma unroll
    for (int ch = 0; ch < 8; ++ch) {
        float d = (xn - (float)(ch * 8) * (1.0f / 63.0f)) * 64.0f;
        float g = __expf(-0.5f * d * d);
        float tt = __expf(fminf(qs * d - 0.5f * qs * qs, 60.f));
#pragma unroll
        for (int j = 0; j < 8; ++j) {
            float4 wa = *(const float4*)&Wrow[(ch * 8 + j) * 4];
            a0 = fmaf(g, wa.x, a0);
            a1 = fmaf(g, wa.y, a1);
            a2 = fmaf(g, wa.z, a2);
            a3 = fmaf(g, wa.w, a3);
            g *= tt; tt *= Qc;
        }
    }
    float p0 = __expf(lkv.x + soft * a0 + baS[sid * 4 + 0]);
    float p1 = __expf(lkv.y + soft * a1 + baS[sid * 4 + 1]);
    float p2 = __expf(lkv.z + soft * a2 + baS[sid * 4 + 2]);
    float p3 = __expf(lkv.w + soft * a3 + baS[sid * 4 + 3]);
    *(float4*)&edP[(size_t)p * 4] = make_float4(p0, p1, p2, p3);
    *(float4*)&edG[(size_t)p * 4] = make_float4(ux, uy, uz, xn);
}

// ---------------------------------------------------------------
// g-fragment via multiply-chain (2 exp per 8 centers), re-seeded per chunk.
__device__ __forceinline__ short8v gchain(float xn, int k0, float soft, float Qc) {
    const float qs = 64.f / 63.f;
    float d = (xn - (float)k0 * (1.0f / 63.0f)) * 64.0f;
    float g = __expf(-0.5f * d * d);
    float tt = __expf(fminf(qs * d - 0.5f * qs * qs, 60.f));
    short8v rr;
#pragma unroll
    for (int j = 0; j < 8; ++j) {
        rr[j] = f2bf(g * soft);
        g *= tt; tt *= Qc;
    }
    return rr;
}

// MFMA edge aggregation: block = 1 dst, 4 waves = (sid, tile-parity).
// V tile staged via dwordx4 gathers -> LDS (272B row stride, conflict-free).
// Denominator reduced in-block (no atomics, deterministic).
__global__ __launch_bounds__(256) void k_main4(
    const int* offsets, const int* packed, const float* edP, const float* edG,
    const unsigned short* Vu, const float* bm, const short* WmF, const short* WshF,
    float* out_pre, int NQr) {
    __shared__ __align__(16) char vtile[4][16 * 272];
    __shared__ float part[4][132];
    int t = threadIdx.x;
    int w = t >> 6, lane = t & 63;
    int dst = blockIdx.x;
    int sid = w & 1, par = w >> 1;
    int m = lane & 15, grp = lane >> 4;

    float acc[8];
#pragma unroll
    for (int i = 0; i < 8; ++i) acc[i] = 0.f;
    float d0a = 0.f, d1a = 0.f, d2a = 0.f, d3a = 0.f;

    int key = sid * NQr + dst;
    int s0 = offsets[key], s1 = offsets[key + 1];
    int n = s1 - s0;

    float bmv[8];
#pragma unroll
    for (int ct = 0; ct < 8; ++ct) bmv[ct] = bm[sid * 128 + ct * 16 + m];

    const float qs = 64.f / 63.f;
    const float Qc = __expf(-qs * qs);
    const float s3 = 1.7320508075688772f, s15 = 3.872983346207417f, s5 = 2.23606797749979f;

    if (n > 0) {
        int ntiles = (n + 15) >> 4;
        for (int tl = par; tl < ntiles; tl += 2) {
            int q0 = s0 + tl * 16;
            int posA = q0 + m; if (posA >= s1) posA = s1 - 1;
            float4 G4 = *(const float4*)&edG[(size_t)posA * 4];
            int src_r[4]; float4 p4[4];
#pragma unroll
            for (int r = 0; r < 4; ++r) {
                int pos = q0 + grp * 4 + r;
                bool valid = pos < s1;
                if (!valid) pos = s1 - 1;
                int wv = packed[pos];
                src_r[r] = wv & 0xFFFF;
                float4 pv = *(const float4*)&edP[(size_t)pos * 4];
                if (!valid) pv = make_float4(0.f, 0.f, 0.f, 0.f);
                p4[r] = pv;
            }
            // stage V tile: inst i stages edge grp*4+i, 16B per lane
#pragma unroll
            for (int i = 0; i < 4; ++i) {
                int4 vv = *(const int4*)&Vu[(size_t)src_r[i] * 128 + m * 8];
                *(int4*)&vtile[w][(grp * 4 + i) * 272 + m * 16] = vv;
            }
#pragma unroll
            for (int r = 0; r < 4; ++r) {
                d0a += p4[r].x; d1a += p4[r].y; d2a += p4[r].z; d3a += p4[r].w;
            }
            // A fragments
            float xn = G4.w;
            float su = fminf(fmaxf((xn - 0.8f) * 5.0f, 0.0f), 1.0f);
            float soft = 0.5f * (1.0f + __cosf(PI_F * su));
            short8v aG0 = gchain(xn, grp * 8, soft, Qc);
            short8v aG1 = gchain(xn, 32 + grp * 8, soft, Qc);

            float ux = G4.x, uy = G4.y, uz = G4.z;
            float sh[9];
            sh[0] = 1.f; sh[1] = s3 * ux; sh[2] = s3 * uy; sh[3] = s3 * uz;
            sh[4] = s15 * ux * uy; sh[5] = s15 * uy * uz;
            sh[6] = 0.5f * s5 * (3.f * uz * uz - 1.f);
            sh[7] = s15 * ux * uz; sh[8] = 0.5f * s15 * (ux * ux - uy * uy);
            short8v aS;
#pragma unroll
            for (int j = 0; j < 8; ++j) {
                float v = (grp == 0) ? sh[j] : ((grp == 1 && j == 0) ? sh[8] : 0.f);
                aS[j] = f2bf(v);
            }

#pragma unroll
            for (int ct = 0; ct < 8; ++ct) {
                short8v b0 = *(const short8v*)&WmF[(((sid * 8 + ct) * 2 + 0) * 64 + lane) * 8];
                short8v b1 = *(const short8v*)&WmF[(((sid * 8 + ct) * 2 + 1) * 64 + lane) * 8];
                short8v bS = *(const short8v*)&WshF[(ct * 64 + lane) * 8];
                f32x4 cms = {0.f, 0.f, 0.f, 0.f};
                cms = __builtin_amdgcn_mfma_f32_16x16x32_bf16(aG0, b0, cms, 0, 0, 0);
                cms = __builtin_amdgcn_mfma_f32_16x16x32_bf16(aG1, b1, cms, 0, 0, 0);
                f32x4 csh = {0.f, 0.f, 0.f, 0.f};
                csh = __builtin_amdgcn_mfma_f32_16x16x32_bf16(aS, bS, csh, 0, 0, 0);
#pragma unroll
                for (int r = 0; r < 4; ++r) {
                    unsigned short vu16 = *(const unsigned short*)
                        &vtile[w][(grp * 4 + r) * 272 + (ct * 16 + m) * 2];
                    float vf = bf2f(vu16);
                    float ms = cms[r] + bmv[ct];
                    float ve = fmaf(vf, ms, csh[r]);
                    float ph = (ct < 2) ? p4[r].x : (ct < 4) ? p4[r].y
                              : (ct < 6) ? p4[r].z : p4[r].w;
                    acc[ct] = fmaf(ph, ve, acc[ct]);
                }
            }
        }
    }

#pragma unroll
    for (int i = 0; i < 8; ++i) {
        acc[i] += __shfl_xor(acc[i], 16);
        acc[i] += __shfl_xor(acc[i], 32);
    }
    d0a += __shfl_xor(d0a, 16); d0a += __shfl_xor(d0a, 32);
    d1a += __shfl_xor(d1a, 16); d1a += __shfl_xor(d1a, 32);
    d2a += __shfl_xor(d2a, 16); d2a += __shfl_xor(d2a, 32);
    d3a += __shfl_xor(d3a, 16); d3a += __shfl_xor(d3a, 32);
    if (lane < 16) {
#pragma unroll
        for (int ct = 0; ct < 8; ++ct) part[w][ct * 16 + lane] = acc[ct];
    }
    if (lane == 0) {
        part[w][128] = d0a; part[w][129] = d1a;
        part[w][130] = d2a; part[w][131] = d3a;
    }
    __syncthreads();
    if (t < 128) {
        float s = part[0][t] + part[1][t] + part[2][t] + part[3][t];
        int h = t >> 5;
        float d = part[0][128 + h] + part[1][128 + h] + part[2][128 + h] + part[3][128 + h];
        out_pre[(size_t)dst * 128 + t] = s / (d + 1e-9f);
    }
}

// ---------------------------------------------------------------
extern "C" void kernel_launch(void* const* d_in, const int* in_sizes, int n_in,
                              void* d_out, int out_size, void* d_ws, size_t ws_size,
                              hipStream_t stream) {
    const float* query_coord = (const float*)d_in[0];
    const float* node_feature = (const float*)d_in[1];
    const float* node_coord = (const float*)d_in[2];
    const int* edge_src = (const int*)d_in[3];
    const int* edge_dst = (const int*)d_in[4];
    const int* scale_id = (const int*)d_in[5];
    const float* b_dst = (const float*)d_in[6];
    const float* Wq = (const float*)d_in[7];
    const float* Wk = (const float*)d_in[8];
    const float* Wv = (const float*)d_in[9];
    const float* Wo = (const float*)d_in[10];
    const float* bo = (const float*)d_in[11];
    const float* W_rad0 = (const float*)d_in[12];
    const float* b_rad0 = (const float*)d_in[13];
    const float* W_rad1 = (const float*)d_in[14];
    const float* b_rad1 = (const float*)d_in[15];
    const float* W_msg = (const float*)d_in[16];
    const float* W_sh = (const float*)d_in[17];
    const float* W_alpha = (const float*)d_in[18];
    (void)n_in; (void)ws_size; (void)out_size;

    int NQr = in_sizes[0] / 3;      // 4096
    int Nn = in_sizes[1] / 128;     // 40960
    int E = in_sizes[3];            // 262144
    int nkey = NQr * 2;

    float* ws = (float*)d_ws;
    float* Wa = ws + WS_WA;
    float* ba = ws + WS_BA;
    float* bm = ws + WS_BM;
    short* WmF = (short*)(ws + WS_WMF);
    short* WshF = (short*)(ws + WS_WSHF);
    short* QKF = (short*)(ws + WS_QKF);
    short* WVF = (short*)(ws + WS_WVF);
    short* WOF = (short*)(ws + WS_WOF);
    int* counts = (int*)(ws + WS_COUNTS);
    int* offsets = (int*)(ws + WS_OFFS);
    int* cursor = (int*)(ws + WS_CURSOR);
    int* packed = (int*)(ws + WS_PACKED);
    float* lk = ws + WS_LK;
    float* edP = ws + WS_EDP;
    float* edG = ws + WS_EDG;
    unsigned short* Vb = (unsigned short*)(ws + WS_VB);
    float* out_pre = ws + WS_OUTPRE;
    float* out = (float*)d_out;

    hipLaunchKernelGGL(k_prepfmt, dim3(209), dim3(256), 0, stream,
                       b_dst, Wq, Wk, W_rad0, b_rad0, W_rad1, b_rad1, W_msg, W_alpha,
                       Wv, Wo, W_sh, Wa, ba, bm, WmF, WshF, QKF, WVF, WOF, counts, nkey);
    hipLaunchKernelGGL(k_hist, dim3((E + 255) / 256), dim3(256), 0, stream,
                       edge_dst, scale_id, counts, E, NQr);
    hipLaunchKernelGGL(k_scan, dim3(1), dim3(256), 0, stream, counts, offsets, cursor, nkey);
    hipLaunchKernelGGL(k_scatter, dim3((E + 255) / 256), dim3(256), 0, stream,
                       edge_src, edge_dst, scale_id, cursor, packed, E, NQr);
    hipLaunchKernelGGL((k_mgemm<unsigned short, true>), dim3((Nn + 63) / 64), dim3(256), 0,
                       stream, node_feature, WVF, (const float*)nullptr, Vb, lk, QKF, Nn);
    hipLaunchKernelGGL(k_edge, dim3((E + 255) / 256), dim3(256), 0, stream,
                       packed, offsets, query_coord, node_coord, lk, Wa, ba,
                       edP, edG, NQr, E);
    hipLaunchKernelGGL(k_main4, dim3(NQr), dim3(256), 0, stream,
                       offsets, packed, edP, edG, Vb, bm, WmF, WshF, out_pre, NQr);
    hipLaunchKernelGGL((k_mgemm<float, false>), dim3((NQr + 63) / 64), dim3(256), 0, stream,
                       out_pre, WOF, bo, out, (float*)nullptr, (const short*)nullptr, NQr);
}